// Round 1
// baseline (139.721 us; speedup 1.0000x reference)
//
#include <hip/hip_runtime.h>
#include <cstdint>

#define NB 8
#define TS 2048
#define NE 1024
#define HD 64
#define MTOT (NB*TS)

typedef float     f4  __attribute__((ext_vector_type(4)));
typedef short     s8v __attribute__((ext_vector_type(8)));
typedef short     s4v __attribute__((ext_vector_type(4)));
typedef int       i4v __attribute__((ext_vector_type(4)));
typedef _Float16  h8  __attribute__((ext_vector_type(8)));

__device__ __forceinline__ short f2bf(float f) {  // RNE
  union { float f; uint32_t u; } x; x.f = f;
  return (short)((x.u + 0x7FFFu + ((x.u >> 16) & 1u)) >> 16);
}

// pack two fp32 -> (bf16(lo) | bf16(hi)<<16) via +0x8000 round + v_perm byte select
__device__ __forceinline__ int pack2(float lo, float hi) {
  union { float f; uint32_t u; } a, b; a.f = lo; b.f = hi;
  return (int)__builtin_amdgcn_perm(b.u + 0x8000u, a.u + 0x8000u, 0x07060302u);
}

// async global->LDS DMA, 16B/lane; lptr wave-uniform, lane i -> lptr + i*16
__device__ __forceinline__ void gl2lds(const void* gptr, void* lptr) {
  auto g = (const __attribute__((address_space(1))) uint32_t*)gptr;
  auto l = (__attribute__((address_space(3))) uint32_t*)lptr;
  __builtin_amdgcn_global_load_lds(g, l, 16, 0, 0);
}

// barrier that keeps N newest vmem ops in flight (AITER-style, never drain unless N=0)
template <int N>
__device__ __forceinline__ void wait_barrier() {
  asm volatile("s_waitcnt vmcnt(%0) lgkmcnt(0)" :: "n"(N) : "memory");
  __builtin_amdgcn_s_barrier();
}

// ---- kernel 0: W fp32 -> bf16 (q-scale folded). wb [192][1024]: 0-63 q, 64-127 k, 128-191 v
__global__ __launch_bounds__(256) void wconv_kernel(
    const float* __restrict__ Wk, const float* __restrict__ Wq, const float* __restrict__ Wv,
    short* __restrict__ wb)
{
  const int idx = (blockIdx.x * 256 + threadIdx.x) * 4;
  const int p = idx >> 16;
  const int off = idx & 65535;
  const float* W = (p == 0) ? Wq : (p == 1) ? Wk : Wv;
  const float s = (p == 0) ? 0.18033688011112042f : 1.0f; // (1/8)*log2(e)
  const float4 v = *(const float4*)&W[off];
  s4v h; h[0] = f2bf(v.x*s); h[1] = f2bf(v.y*s); h[2] = f2bf(v.z*s); h[3] = f2bf(v.w*s);
  *(s4v*)&wb[idx] = h;
}

// ---- kernel 1: fused qkv projection. grid 512 x 256 thr, tile 32 rows x 192 cols,
// wave = 16 rows x 96 cols. LDS exactly 80 KB -> 2 blocks/CU (8 waves/CU).
// x: 4-buf fp32 DMA (3-ahead issue); W: 2-buf bf16 DMA (1-ahead). XOR slot-swizzle.
__global__ __launch_bounds__(256) void proj_kernel(
    const float* __restrict__ x, const short* __restrict__ wb,
    short* __restrict__ qo, short* __restrict__ ko, _Float16* __restrict__ vo)
{
  __shared__ float Xs[4][32][64];    // 32 KB
  __shared__ short Ws[2][192][64];   // 48 KB
  const int tid = threadIdx.x;
  const int wv = tid >> 6, lane = tid & 63, n = lane & 15, quad = lane >> 4;
  const int mg = wv & 1, cg = wv >> 1;
  const int r0 = blockIdx.x * 32;
  const int xrow = lane >> 4, xslot = lane & 15;   // x DMA: 4 rows x 16 slots (16B fp32)
  const int wrow = lane >> 3, wslot = lane & 7;    // W DMA: 8 cols x 8 slots (16B bf16)

  auto dmaX = [&](int c, int buf) {
#pragma unroll
    for (int u = 0; u < 2; ++u) {
      const int R0 = (wv * 2 + u) * 4;
      const int row = R0 + xrow;
      const int gs = (xslot + row) & 15;
      gl2lds(&x[(size_t)(r0 + row) * NE + c * 64 + gs * 4], &Xs[buf][R0][0]);
    }
  };
  auto dmaW = [&](int c, int buf) {
#pragma unroll
    for (int u = 0; u < 6; ++u) {
      const int C0 = (wv * 6 + u) * 8;
      const int col = C0 + wrow;
      const int gs = (wslot + col) & 7;
      gl2lds(&wb[(size_t)col * NE + c * 64 + gs * 8], &Ws[buf][C0][0]);
    }
  };

  const f4 fz = {0.f, 0.f, 0.f, 0.f};
  f4 acc[6] = {fz, fz, fz, fz, fz, fz};

  auto compute = [&](int bw, int bx) {
    s8v a[2];
    const int row = mg * 16 + n;
#pragma unroll
    for (int kc = 0; kc < 2; ++kc) {
      const int u0 = kc * 8 + quad * 2;
      const float* pr = &Xs[bx][row][0];
      const f4 f0 = *(const f4*)(pr + (((u0    ) - row) & 15) * 4);
      const f4 f1 = *(const f4*)(pr + (((u0 + 1) - row) & 15) * 4);
      i4v ai;
      ai[0] = pack2(f0[0], f0[1]); ai[1] = pack2(f0[2], f0[3]);
      ai[2] = pack2(f1[0], f1[1]); ai[3] = pack2(f1[2], f1[3]);
      a[kc] = __builtin_bit_cast(s8v, ai);
    }
#pragma unroll
    for (int nf = 0; nf < 6; ++nf) {
      const int col = cg * 96 + nf * 16 + n;
      const s8v b0 = *(const s8v*)&Ws[bw][col][(((0 + quad) - col) & 7) * 8];
      const s8v b1 = *(const s8v*)&Ws[bw][col][(((4 + quad) - col) & 7) * 8];
      acc[nf] = __builtin_amdgcn_mfma_f32_16x16x32_bf16(a[0], b0, acc[nf], 0, 0, 0);
      acc[nf] = __builtin_amdgcn_mfma_f32_16x16x32_bf16(a[1], b1, acc[nf], 0, 0, 0);
    }
  };

  // prologue: W0 first, then X0..X2 (FIFO: waiting for X0 keeps X1,X2 in flight)
  dmaW(0, 0); dmaX(0, 0); dmaX(1, 1); dmaX(2, 2);
  wait_barrier<4>();

  for (int t = 0; t < 16; ++t) {
    if (t <= 14) dmaW(t + 1, (t + 1) & 1);   // W first (older in FIFO than this iter's X)
    if (t <= 12) dmaX(t + 3, (t + 3) & 3);
    compute(t & 1, t & 3);
    if (t <= 12)      wait_barrier<2>();     // keep X(t+3) flying; X(t+1),W(t+1) landed
    else if (t <= 14) wait_barrier<0>();     // tail
  }

  // epilogue: C row = quad*4+i, col = n (+16*nf)
#pragma unroll
  for (int nf = 0; nf < 6; ++nf) {
    const int gc = cg * 96 + nf * 16;
    const int p = gc >> 6;
    const int rcol = (gc & 63) + n;
#pragma unroll
    for (int i = 0; i < 4; ++i) {
      const int R = r0 + mg * 16 + quad * 4 + i;
      const float av = acc[nf][i];
      if (p == 0)      qo[(size_t)R * HD + rcol] = f2bf(av);
      else if (p == 1) ko[(size_t)R * HD + rcol] = f2bf(av);
      else {
        // V transposed [b][d][t'] + key-order swizzle so attn PV B-frags are single 16B loads
        const int t2 = R & (TS - 1), b = t2 & 31;
        const int pos = (t2 & ~31) | (((b >> 2) & 3) << 3) | (((b >> 4) & 1) << 2) | (b & 3);
        vo[(size_t)(R >> 11) * HD * TS + (size_t)rcol * TS + pos] = (_Float16)av;
      }
    }
  }
}

// ---- kernel 2: attention. grid 256 x 512 thr (8 waves). 64 q/block.
// Waves = 2 q-groups (32 q) x 4 key-quarters (512 keys = 8 chunks of 64).
// K staged in LDS: [4 quarters][3 bufs][64][64] bf16 = 96 KB, 2-ahead DMA (vmcnt(4)).
// V read DIRECTLY from L2 (key-order swizzle makes PV B-frags single 16B global loads);
// each V element only had 2 LDS consumers, so staging was pure overhead.
// 32 q/wave: each kf/vf fragment feeds 2 q-groups -> LDS read traffic 2MB -> 0.5MB/block.
// S^T = K Q^T -> exp2 in-reg -> f16 PV; l via P*ones. 4-way combine in LDS overlay.
__global__ __launch_bounds__(512) void attn_kernel(
    const short* __restrict__ q, const short* __restrict__ k,
    const _Float16* __restrict__ vT, float* __restrict__ out)
{
  __shared__ __align__(16) char smem[98304];   // K[4][3][64][64] bf16 | overlay o_c/l_c
  const int tid = threadIdx.x;
  const int wv = tid >> 6, lane = tid & 63, n = lane & 15, quad = lane >> 4;
  const int kq = wv & 3, qg = wv >> 2;         // key-quarter, q-group
  const int batch = blockIdx.x & 7;            // XCD swizzle: batch K/V pinned per XCD L2
  const int qgb = blockIdx.x >> 3;
  const int m0 = batch * TS + qgb * 64;
  const short*    kb = k  + (size_t)batch * TS * HD;
  const _Float16* vb = vT + (size_t)batch * HD * TS;
  const int drow = lane >> 3, dslot = lane & 7;
  const f4 fz = {0.f, 0.f, 0.f, 0.f};

  auto kbuf = [&](int buf) { return (short*)(smem + (kq * 3 + buf) * 8192); };

  // stage one 64-key K chunk for this quarter; 2 waves (qg 0/1) split the 8 rows-of-8
  auto dmaK = [&](int tt, int buf) {
    const int c = kq * 8 + tt;
#pragma unroll
    for (int u = 0; u < 4; ++u) {
      const int K0 = (qg * 4 + u) * 8;
      const int key = K0 + drow;
      const int gs = (dslot + key) & 7;
      gl2lds(&kb[(size_t)(c * 64 + key) * HD + gs * 8], kbuf(buf) + K0 * 64);
    }
  };

  s8v qf[2][2];
#pragma unroll
  for (int qh = 0; qh < 2; ++qh)
#pragma unroll
    for (int kc = 0; kc < 2; ++kc)
      qf[qh][kc] = *(const s8v*)&q[(size_t)(m0 + qg * 32 + qh * 16 + n) * HD + kc * 32 + quad * 8];

  f4 o[2][4] = {{fz, fz, fz, fz}, {fz, fz, fz, fz}};
  f4 lD[2] = {fz, fz};
  h8 ones;
#pragma unroll
  for (int j = 0; j < 8; ++j) ones[j] = (_Float16)1.0f;

  dmaK(0, 0); dmaK(1, 1);
  wait_barrier<4>();

  for (int t = 0; t < 8; ++t) {
    const int buf = t % 3;
    const int c = kq * 8 + t;

    // V frags direct from global/L2 — issued FIRST so they are older in the vmem FIFO
    // than this iter's prefetch DMA (their consumption waits then keep the DMA flying)
    h8 vfr[2][4];
#pragma unroll
    for (int pr = 0; pr < 2; ++pr)
#pragma unroll
      for (int g = 0; g < 4; ++g)
        vfr[pr][g] = *(const h8*)&vb[(size_t)(g * 16 + n) * TS + c * 64 + (pr * 4 + quad) * 8];

    if (t <= 5) dmaK(t + 2, (t + 2) % 3);

    const short* ks = kbuf(buf);
    s8v kf[4][2];
#pragma unroll
    for (int f = 0; f < 4; ++f)
#pragma unroll
      for (int kc = 0; kc < 2; ++kc) {
        const int key = f * 16 + n;
        kf[f][kc] = *(const s8v*)&ks[key * 64 + (((kc * 4 + quad) - key) & 7) * 8];
      }

    f4 st[2][4];
#pragma unroll
    for (int qh = 0; qh < 2; ++qh)
#pragma unroll
      for (int f = 0; f < 4; ++f) {
        st[qh][f] = __builtin_amdgcn_mfma_f32_16x16x32_bf16(kf[f][0], qf[qh][0], fz, 0, 0, 0);
        st[qh][f] = __builtin_amdgcn_mfma_f32_16x16x32_bf16(kf[f][1], qf[qh][1], st[qh][f], 0, 0, 0);
      }

    h8 pa[2][2];
#pragma unroll
    for (int qh = 0; qh < 2; ++qh)
#pragma unroll
      for (int pr = 0; pr < 2; ++pr)
#pragma unroll
        for (int hf = 0; hf < 2; ++hf)
#pragma unroll
          for (int i = 0; i < 4; ++i)
            pa[qh][pr][hf * 4 + i] = (_Float16)__builtin_amdgcn_exp2f(st[qh][pr * 2 + hf][i]);

#pragma unroll
    for (int pr = 0; pr < 2; ++pr) {
#pragma unroll
      for (int qh = 0; qh < 2; ++qh)
        lD[qh] = __builtin_amdgcn_mfma_f32_16x16x32_f16(pa[qh][pr], ones, lD[qh], 0, 0, 0);
#pragma unroll
      for (int g = 0; g < 4; ++g)
#pragma unroll
        for (int qh = 0; qh < 2; ++qh)
          o[qh][g] = __builtin_amdgcn_mfma_f32_16x16x32_f16(pa[qh][pr], vfr[pr][g], o[qh][g], 0, 0, 0);
    }

    if (t <= 5)      wait_barrier<4>();   // chunk t+1 landed; t+2 stays in flight
    else if (t == 6) wait_barrier<0>();
  }

  __syncthreads();   // all waves done with K LDS before overlay

  float* o_c = (float*)smem;              // [4 kq][64 q][68]  (68 pad: 2-way banks, 16B-aligned)
  float* l_c = (float*)(smem + 69632);    // [4 kq][64 q]
  if (n == 0)
#pragma unroll
    for (int qh = 0; qh < 2; ++qh)
#pragma unroll
      for (int i = 0; i < 4; ++i)
        l_c[kq * 64 + qg * 32 + qh * 16 + quad * 4 + i] = lD[qh][i];
#pragma unroll
  for (int qh = 0; qh < 2; ++qh)
#pragma unroll
    for (int g = 0; g < 4; ++g)
#pragma unroll
      for (int i = 0; i < 4; ++i)
        o_c[kq * 4352 + (qg * 32 + qh * 16 + quad * 4 + i) * 68 + g * 16 + n] = o[qh][g][i];
  __syncthreads();

  // combine quarters: 1024 output-groups (64 q x 16 d4), 512 thr x 2 reps
#pragma unroll
  for (int rep = 0; rep < 2; ++rep) {
    const int idx = tid + rep * 512;
    const int qr = idx >> 4, d4 = (idx & 15) * 4;
    float L = 0.f;
    f4 r = fz;
#pragma unroll
    for (int c2 = 0; c2 < 4; ++c2) {
      L += l_c[c2 * 64 + qr];
      r += *(const f4*)&o_c[c2 * 4352 + qr * 68 + d4];
    }
    const float inv = 1.0f / L;
    r[0] *= inv; r[1] *= inv; r[2] *= inv; r[3] *= inv;
    *(f4*)&out[(size_t)(m0 + qr) * HD + d4] = r;
  }
}

extern "C" void kernel_launch(void* const* d_in, const int* in_sizes, int n_in,
                              void* d_out, int out_size, void* d_ws, size_t ws_size,
                              hipStream_t stream) {
  const float* x  = (const float*)d_in[0];
  const float* Wk = (const float*)d_in[1];
  const float* Wq = (const float*)d_in[2];
  const float* Wv = (const float*)d_in[3];
  float* out = (float*)d_out;

  short* qb = (short*)d_ws;                           // [MTOT][64] bf16 (pre-scaled)
  short* kb = qb + (size_t)MTOT * HD;                 // [MTOT][64] bf16
  _Float16* vb = (_Float16*)(kb + (size_t)MTOT * HD); // [NB][64][TS] f16, key-swizzled
  short* wb = (short*)(vb + (size_t)NB * HD * TS);    // [192][1024] bf16 weights

  wconv_kernel<<<192, 256, 0, stream>>>(Wk, Wq, Wv, wb);
  proj_kernel<<<MTOT / 32, 256, 0, stream>>>(x, wb, qb, kb, vb);
  attn_kernel<<<MTOT / 64, 512, 0, stream>>>(qb, kb, vb, out);
}

// Round 2
// 128.894 us; speedup vs baseline: 1.0840x; 1.0840x over previous
//
#include <hip/hip_runtime.h>
#include <cstdint>

#define NB 8
#define TS 2048
#define NE 1024
#define HD 64
#define MTOT (NB*TS)

typedef float     f4  __attribute__((ext_vector_type(4)));
typedef short     s8v __attribute__((ext_vector_type(8)));
typedef short     s4v __attribute__((ext_vector_type(4)));
typedef int       i4v __attribute__((ext_vector_type(4)));
typedef _Float16  h8  __attribute__((ext_vector_type(8)));

__device__ __forceinline__ short f2bf(float f) {  // RNE
  union { float f; uint32_t u; } x; x.f = f;
  return (short)((x.u + 0x7FFFu + ((x.u >> 16) & 1u)) >> 16);
}

// pack two fp32 -> (bf16(lo) | bf16(hi)<<16) via +0x8000 round + v_perm byte select
__device__ __forceinline__ int pack2(float lo, float hi) {
  union { float f; uint32_t u; } a, b; a.f = lo; b.f = hi;
  return (int)__builtin_amdgcn_perm(b.u + 0x8000u, a.u + 0x8000u, 0x07060302u);
}

// async global->LDS DMA, 16B/lane; lptr wave-uniform, lane i -> lptr + i*16
__device__ __forceinline__ void gl2lds(const void* gptr, void* lptr) {
  auto g = (const __attribute__((address_space(1))) uint32_t*)gptr;
  auto l = (__attribute__((address_space(3))) uint32_t*)lptr;
  __builtin_amdgcn_global_load_lds(g, l, 16, 0, 0);
}

// barrier that keeps N newest vmem ops in flight (AITER-style, never drain unless N=0)
template <int N>
__device__ __forceinline__ void wait_barrier() {
  asm volatile("s_waitcnt vmcnt(%0) lgkmcnt(0)" :: "n"(N) : "memory");
  __builtin_amdgcn_s_barrier();
}

// lgkm-only barrier: all waves' LDS reads retired; vmem prefetches stay in flight
__device__ __forceinline__ void lds_done_barrier() {
  asm volatile("s_waitcnt lgkmcnt(0)" ::: "memory");
  __builtin_amdgcn_s_barrier();
}

// ---- kernel 0: W fp32 -> bf16 (q-scale folded). wb [192][1024]: 0-63 q, 64-127 k, 128-191 v
__global__ __launch_bounds__(256) void wconv_kernel(
    const float* __restrict__ Wk, const float* __restrict__ Wq, const float* __restrict__ Wv,
    short* __restrict__ wb)
{
  const int idx = (blockIdx.x * 256 + threadIdx.x) * 4;
  const int p = idx >> 16;
  const int off = idx & 65535;
  const float* W = (p == 0) ? Wq : (p == 1) ? Wk : Wv;
  const float s = (p == 0) ? 0.18033688011112042f : 1.0f; // (1/8)*log2(e)
  const float4 v = *(const float4*)&W[off];
  s4v h; h[0] = f2bf(v.x*s); h[1] = f2bf(v.y*s); h[2] = f2bf(v.z*s); h[3] = f2bf(v.w*s);
  *(s4v*)&wb[idx] = h;
}

// ---- kernel 1: fused qkv projection. grid 512 x 256 thr, tile 32 rows x 192 cols,
// wave = 16 rows x 96 cols. LDS exactly 80 KB -> 2 blocks/CU (8 waves/CU).
// x: 4-buf fp32 DMA (3-ahead issue); W: 2-buf bf16 DMA (1-ahead). XOR slot-swizzle.
__global__ __launch_bounds__(256) void proj_kernel(
    const float* __restrict__ x, const short* __restrict__ wb,
    short* __restrict__ qo, short* __restrict__ ko, _Float16* __restrict__ vo)
{
  __shared__ float Xs[4][32][64];    // 32 KB
  __shared__ short Ws[2][192][64];   // 48 KB
  const int tid = threadIdx.x;
  const int wv = tid >> 6, lane = tid & 63, n = lane & 15, quad = lane >> 4;
  const int mg = wv & 1, cg = wv >> 1;
  const int r0 = blockIdx.x * 32;
  const int xrow = lane >> 4, xslot = lane & 15;   // x DMA: 4 rows x 16 slots (16B fp32)
  const int wrow = lane >> 3, wslot = lane & 7;    // W DMA: 8 cols x 8 slots (16B bf16)

  auto dmaX = [&](int c, int buf) {
#pragma unroll
    for (int u = 0; u < 2; ++u) {
      const int R0 = (wv * 2 + u) * 4;
      const int row = R0 + xrow;
      const int gs = (xslot + row) & 15;
      gl2lds(&x[(size_t)(r0 + row) * NE + c * 64 + gs * 4], &Xs[buf][R0][0]);
    }
  };
  auto dmaW = [&](int c, int buf) {
#pragma unroll
    for (int u = 0; u < 6; ++u) {
      const int C0 = (wv * 6 + u) * 8;
      const int col = C0 + wrow;
      const int gs = (wslot + col) & 7;
      gl2lds(&wb[(size_t)col * NE + c * 64 + gs * 8], &Ws[buf][C0][0]);
    }
  };

  const f4 fz = {0.f, 0.f, 0.f, 0.f};
  f4 acc[6] = {fz, fz, fz, fz, fz, fz};

  auto compute = [&](int bw, int bx) {
    s8v a[2];
    const int row = mg * 16 + n;
#pragma unroll
    for (int kc = 0; kc < 2; ++kc) {
      const int u0 = kc * 8 + quad * 2;
      const float* pr = &Xs[bx][row][0];
      const f4 f0 = *(const f4*)(pr + (((u0    ) - row) & 15) * 4);
      const f4 f1 = *(const f4*)(pr + (((u0 + 1) - row) & 15) * 4);
      i4v ai;
      ai[0] = pack2(f0[0], f0[1]); ai[1] = pack2(f0[2], f0[3]);
      ai[2] = pack2(f1[0], f1[1]); ai[3] = pack2(f1[2], f1[3]);
      a[kc] = __builtin_bit_cast(s8v, ai);
    }
#pragma unroll
    for (int nf = 0; nf < 6; ++nf) {
      const int col = cg * 96 + nf * 16 + n;
      const s8v b0 = *(const s8v*)&Ws[bw][col][(((0 + quad) - col) & 7) * 8];
      const s8v b1 = *(const s8v*)&Ws[bw][col][(((4 + quad) - col) & 7) * 8];
      acc[nf] = __builtin_amdgcn_mfma_f32_16x16x32_bf16(a[0], b0, acc[nf], 0, 0, 0);
      acc[nf] = __builtin_amdgcn_mfma_f32_16x16x32_bf16(a[1], b1, acc[nf], 0, 0, 0);
    }
  };

  // prologue: W0 first, then X0..X2 (FIFO: waiting for X0 keeps X1,X2 in flight)
  dmaW(0, 0); dmaX(0, 0); dmaX(1, 1); dmaX(2, 2);
  wait_barrier<4>();

  for (int t = 0; t < 16; ++t) {
    if (t <= 14) dmaW(t + 1, (t + 1) & 1);   // W first (older in FIFO than this iter's X)
    if (t <= 12) dmaX(t + 3, (t + 3) & 3);
    compute(t & 1, t & 3);
    if (t <= 12)      wait_barrier<2>();     // keep X(t+3) flying; X(t+1),W(t+1) landed
    else if (t <= 14) wait_barrier<0>();     // tail
  }

  // epilogue: C row = quad*4+i, col = n (+16*nf)
#pragma unroll
  for (int nf = 0; nf < 6; ++nf) {
    const int gc = cg * 96 + nf * 16;
    const int p = gc >> 6;
    const int rcol = (gc & 63) + n;
#pragma unroll
    for (int i = 0; i < 4; ++i) {
      const int R = r0 + mg * 16 + quad * 4 + i;
      const float av = acc[nf][i];
      if (p == 0)      qo[(size_t)R * HD + rcol] = f2bf(av);
      else if (p == 1) ko[(size_t)R * HD + rcol] = f2bf(av);
      else {
        // V transposed [b][d][t'] + key-order swizzle so attn PV B-frags are single 16B loads
        const int t2 = R & (TS - 1), b = t2 & 31;
        const int pos = (t2 & ~31) | (((b >> 2) & 3) << 3) | (((b >> 4) & 1) << 2) | (b & 3);
        vo[(size_t)(R >> 11) * HD * TS + (size_t)rcol * TS + pos] = (_Float16)av;
      }
    }
  }
}

// ---- kernel 2: attention. grid 256 x 512 thr (8 waves). 64 q/block.
// Waves = 2 q-groups (32 q each) x 4 key-quarters (512 keys = 8 chunks of 64).
// K AND V both staged in LDS (V-direct-from-L2 regressed: reg spills + exposed L2 latency).
// Per quarter: K[2][64][64]bf16 + V[2][64][64]f16, 2-buf each -> 128 KB total, 1 block/CU.
// 32 q/wave: each kf/vf LDS fragment feeds 2 q-groups -> LDS read traffic 2MB -> 1MB/block.
// 2-buf discipline: lgkm-only barrier after compute (readers done), THEN re-issue DMA into
// the consumed buffer, THEN vmcnt(8) barrier (next chunk landed; prefetch stays in flight).
// S^T = K Q^T -> exp2 in-reg -> f16 PV; l via P*ones. 4-way combine in LDS overlay.
__global__ __launch_bounds__(512) void attn_kernel(
    const short* __restrict__ q, const short* __restrict__ k,
    const _Float16* __restrict__ vT, float* __restrict__ out)
{
  __shared__ __align__(16) char smem[131072];  // K[4][2][64][64]s (64KB) | V[4][2][64][64]h (64KB)
  const int tid = threadIdx.x;
  const int wv = tid >> 6, lane = tid & 63, n = lane & 15, quad = lane >> 4;
  const int kq = wv & 3, qg = wv >> 2;         // key-quarter, q-group
  const int batch = blockIdx.x & 7;            // XCD swizzle: batch K/V pinned per XCD L2
  const int qgb = blockIdx.x >> 3;
  const int m0 = batch * TS + qgb * 64;
  const short*    kb = k  + (size_t)batch * TS * HD;
  const _Float16* vb = vT + (size_t)batch * HD * TS;
  const int drow = lane >> 3, dslot = lane & 7;
  const f4 fz = {0.f, 0.f, 0.f, 0.f};

  auto kbuf = [&](int buf) { return (short*)   (smem +         (kq * 2 + buf) * 8192); };
  auto vbuf = [&](int buf) { return (_Float16*)(smem + 65536 + (kq * 2 + buf) * 8192); };

  // stage one 64-key K+V chunk for this quarter; 2 waves (qg 0/1) split rows 4 ways each
  auto dmaKV = [&](int tt, int buf) {
    const int c = kq * 8 + tt;
#pragma unroll
    for (int u = 0; u < 4; ++u) {
      const int K0 = (qg * 4 + u) * 8;
      const int key = K0 + drow;
      const int gs = (dslot + key) & 7;
      gl2lds(&kb[(size_t)(c * 64 + key) * HD + gs * 8], kbuf(buf) + K0 * 64);
    }
#pragma unroll
    for (int u = 0; u < 4; ++u) {
      const int D0 = (qg * 4 + u) * 8;
      const int d = D0 + drow;
      const int gs = (dslot + d) & 7;
      gl2lds(&vb[(size_t)d * TS + c * 64 + gs * 8], vbuf(buf) + D0 * 64);
    }
  };

  s8v qf[2][2];
#pragma unroll
  for (int qh = 0; qh < 2; ++qh)
#pragma unroll
    for (int kc = 0; kc < 2; ++kc)
      qf[qh][kc] = *(const s8v*)&q[(size_t)(m0 + qg * 32 + qh * 16 + n) * HD + kc * 32 + quad * 8];

  f4 o[2][4] = {{fz, fz, fz, fz}, {fz, fz, fz, fz}};
  f4 lD[2] = {fz, fz};
  h8 ones;
#pragma unroll
  for (int j = 0; j < 8; ++j) ones[j] = (_Float16)1.0f;

  dmaKV(0, 0); dmaKV(1, 1);   // 8 ops each
  wait_barrier<8>();          // chunk 0 landed; chunk 1's 8 ops in flight

  for (int t = 0; t < 8; ++t) {
    const int buf = t & 1;
    const short*    ks = kbuf(buf);
    const _Float16* vs = vbuf(buf);

    // QK^T: per key-fragment, feed both q-groups immediately (short kf live range)
    f4 st[2][4];
#pragma unroll
    for (int f = 0; f < 4; ++f) {
      const int key = f * 16 + n;
      const s8v k0 = *(const s8v*)&ks[key * 64 + (((0 + quad) - key) & 7) * 8];
      const s8v k1 = *(const s8v*)&ks[key * 64 + (((4 + quad) - key) & 7) * 8];
#pragma unroll
      for (int qh = 0; qh < 2; ++qh) {
        st[qh][f] = __builtin_amdgcn_mfma_f32_16x16x32_bf16(k0, qf[qh][0], fz, 0, 0, 0);
        st[qh][f] = __builtin_amdgcn_mfma_f32_16x16x32_bf16(k1, qf[qh][1], st[qh][f], 0, 0, 0);
      }
    }

    h8 pa[2][2];
#pragma unroll
    for (int qh = 0; qh < 2; ++qh)
#pragma unroll
      for (int pr = 0; pr < 2; ++pr)
#pragma unroll
        for (int hf = 0; hf < 2; ++hf)
#pragma unroll
          for (int i = 0; i < 4; ++i)
            pa[qh][pr][hf * 4 + i] = (_Float16)__builtin_amdgcn_exp2f(st[qh][pr * 2 + hf][i]);

#pragma unroll
    for (int pr = 0; pr < 2; ++pr) {
#pragma unroll
      for (int qh = 0; qh < 2; ++qh)
        lD[qh] = __builtin_amdgcn_mfma_f32_16x16x32_f16(pa[qh][pr], ones, lD[qh], 0, 0, 0);
#pragma unroll
      for (int g = 0; g < 4; ++g) {
        const int d = g * 16 + n;
        const h8 vf = *(const h8*)&vs[d * 64 + (((pr * 4 + quad) - d) & 7) * 8];
#pragma unroll
        for (int qh = 0; qh < 2; ++qh)
          o[qh][g] = __builtin_amdgcn_mfma_f32_16x16x32_f16(pa[qh][pr], vf, o[qh][g], 0, 0, 0);
      }
    }

    if (t <= 5) {
      lds_done_barrier();       // all readers of buf done; chunk t+1 stays in flight
      dmaKV(t + 2, buf);        // overwrite just-consumed buffer
      wait_barrier<8>();        // chunk t+1 landed; chunk t+2's 8 ops keep flying
    } else if (t == 6) {
      wait_barrier<0>();        // chunk 7 landed (nothing else in flight)
    }
  }

  __syncthreads();   // all waves done with K/V LDS before overlay

  float* o_c = (float*)smem;              // [4 kq][64 q][68]  (68 pad: 2-way banks, 16B-aligned)
  float* l_c = (float*)(smem + 69632);    // [4 kq][64 q]
  if (n == 0)
#pragma unroll
    for (int qh = 0; qh < 2; ++qh)
#pragma unroll
      for (int i = 0; i < 4; ++i)
        l_c[kq * 64 + qg * 32 + qh * 16 + quad * 4 + i] = lD[qh][i];
#pragma unroll
  for (int qh = 0; qh < 2; ++qh)
#pragma unroll
    for (int g = 0; g < 4; ++g)
#pragma unroll
      for (int i = 0; i < 4; ++i)
        o_c[kq * 4352 + (qg * 32 + qh * 16 + quad * 4 + i) * 68 + g * 16 + n] = o[qh][g][i];
  __syncthreads();

  // combine quarters: 1024 output-groups (64 q x 16 d4), 512 thr x 2 reps
#pragma unroll
  for (int rep = 0; rep < 2; ++rep) {
    const int idx = tid + rep * 512;
    const int qr = idx >> 4, d4 = (idx & 15) * 4;
    float L = 0.f;
    f4 r = fz;
#pragma unroll
    for (int c2 = 0; c2 < 4; ++c2) {
      L += l_c[c2 * 64 + qr];
      r += *(const f4*)&o_c[c2 * 4352 + qr * 68 + d4];
    }
    const float inv = 1.0f / L;
    r[0] *= inv; r[1] *= inv; r[2] *= inv; r[3] *= inv;
    *(f4*)&out[(size_t)(m0 + qr) * HD + d4] = r;
  }
}

extern "C" void kernel_launch(void* const* d_in, const int* in_sizes, int n_in,
                              void* d_out, int out_size, void* d_ws, size_t ws_size,
                              hipStream_t stream) {
  const float* x  = (const float*)d_in[0];
  const float* Wk = (const float*)d_in[1];
  const float* Wq = (const float*)d_in[2];
  const float* Wv = (const float*)d_in[3];
  float* out = (float*)d_out;

  short* qb = (short*)d_ws;                           // [MTOT][64] bf16 (pre-scaled)
  short* kb = qb + (size_t)MTOT * HD;                 // [MTOT][64] bf16
  _Float16* vb = (_Float16*)(kb + (size_t)MTOT * HD); // [NB][64][TS] f16, key-swizzled
  short* wb = (short*)(vb + (size_t)NB * HD * TS);    // [192][1024] bf16 weights

  wconv_kernel<<<192, 256, 0, stream>>>(Wk, Wq, Wv, wb);
  proj_kernel<<<MTOT / 32, 256, 0, stream>>>(x, wb, qb, kb, vb);
  attn_kernel<<<MTOT / 64, 512, 0, stream>>>(qb, kb, vb, out);
}

// Round 3
// 126.696 us; speedup vs baseline: 1.1028x; 1.0174x over previous
//
#include <hip/hip_runtime.h>
#include <cstdint>

#define NB 8
#define TS 2048
#define NE 1024
#define HD 64
#define MTOT (NB*TS)

typedef float     f4  __attribute__((ext_vector_type(4)));
typedef short     s8v __attribute__((ext_vector_type(8)));
typedef short     s4v __attribute__((ext_vector_type(4)));
typedef int       i4v __attribute__((ext_vector_type(4)));
typedef _Float16  h8  __attribute__((ext_vector_type(8)));

__device__ __forceinline__ short f2bf(float f) {  // RNE
  union { float f; uint32_t u; } x; x.f = f;
  return (short)((x.u + 0x7FFFu + ((x.u >> 16) & 1u)) >> 16);
}

// pack two fp32 -> (bf16(lo) | bf16(hi)<<16) via +0x8000 round + v_perm byte select
__device__ __forceinline__ int pack2(float lo, float hi) {
  union { float f; uint32_t u; } a, b; a.f = lo; b.f = hi;
  return (int)__builtin_amdgcn_perm(b.u + 0x8000u, a.u + 0x8000u, 0x07060302u);
}

// async global->LDS DMA, 16B/lane; lptr wave-uniform, lane i -> lptr + i*16
__device__ __forceinline__ void gl2lds(const void* gptr, void* lptr) {
  auto g = (const __attribute__((address_space(1))) uint32_t*)gptr;
  auto l = (__attribute__((address_space(3))) uint32_t*)lptr;
  __builtin_amdgcn_global_load_lds(g, l, 16, 0, 0);
}

// barrier that keeps N newest vmem ops in flight (AITER-style, never drain unless N=0)
template <int N>
__device__ __forceinline__ void wait_barrier() {
  asm volatile("s_waitcnt vmcnt(%0) lgkmcnt(0)" :: "n"(N) : "memory");
  __builtin_amdgcn_s_barrier();
}

// ---- kernel 0: W fp32 -> bf16 (q-scale folded). wb [192][1024]: 0-63 q, 64-127 k, 128-191 v
__global__ __launch_bounds__(256) void wconv_kernel(
    const float* __restrict__ Wk, const float* __restrict__ Wq, const float* __restrict__ Wv,
    short* __restrict__ wb)
{
  const int idx = (blockIdx.x * 256 + threadIdx.x) * 4;
  const int p = idx >> 16;
  const int off = idx & 65535;
  const float* W = (p == 0) ? Wq : (p == 1) ? Wk : Wv;
  const float s = (p == 0) ? 0.18033688011112042f : 1.0f; // (1/8)*log2(e)
  const float4 v = *(const float4*)&W[off];
  s4v h; h[0] = f2bf(v.x*s); h[1] = f2bf(v.y*s); h[2] = f2bf(v.z*s); h[3] = f2bf(v.w*s);
  *(s4v*)&wb[idx] = h;
}

// ---- kernel 1: fused qkv projection. grid 512 x 256 thr, tile 32 rows x 192 cols,
// wave = 16 rows x 96 cols. LDS exactly 80 KB -> 2 blocks/CU (8 waves/CU).
// x: 4-buf fp32 DMA (3-ahead issue); W: 2-buf bf16 DMA (1-ahead). XOR slot-swizzle.
__global__ __launch_bounds__(256) void proj_kernel(
    const float* __restrict__ x, const short* __restrict__ wb,
    short* __restrict__ qo, short* __restrict__ ko, _Float16* __restrict__ vo)
{
  __shared__ float Xs[4][32][64];    // 32 KB
  __shared__ short Ws[2][192][64];   // 48 KB
  const int tid = threadIdx.x;
  const int wv = tid >> 6, lane = tid & 63, n = lane & 15, quad = lane >> 4;
  const int mg = wv & 1, cg = wv >> 1;
  const int r0 = blockIdx.x * 32;
  const int xrow = lane >> 4, xslot = lane & 15;   // x DMA: 4 rows x 16 slots (16B fp32)
  const int wrow = lane >> 3, wslot = lane & 7;    // W DMA: 8 cols x 8 slots (16B bf16)

  auto dmaX = [&](int c, int buf) {
#pragma unroll
    for (int u = 0; u < 2; ++u) {
      const int R0 = (wv * 2 + u) * 4;
      const int row = R0 + xrow;
      const int gs = (xslot + row) & 15;
      gl2lds(&x[(size_t)(r0 + row) * NE + c * 64 + gs * 4], &Xs[buf][R0][0]);
    }
  };
  auto dmaW = [&](int c, int buf) {
#pragma unroll
    for (int u = 0; u < 6; ++u) {
      const int C0 = (wv * 6 + u) * 8;
      const int col = C0 + wrow;
      const int gs = (wslot + col) & 7;
      gl2lds(&wb[(size_t)col * NE + c * 64 + gs * 8], &Ws[buf][C0][0]);
    }
  };

  const f4 fz = {0.f, 0.f, 0.f, 0.f};
  f4 acc[6] = {fz, fz, fz, fz, fz, fz};

  auto compute = [&](int bw, int bx) {
    s8v a[2];
    const int row = mg * 16 + n;
#pragma unroll
    for (int kc = 0; kc < 2; ++kc) {
      const int u0 = kc * 8 + quad * 2;
      const float* pr = &Xs[bx][row][0];
      const f4 f0 = *(const f4*)(pr + (((u0    ) - row) & 15) * 4);
      const f4 f1 = *(const f4*)(pr + (((u0 + 1) - row) & 15) * 4);
      i4v ai;
      ai[0] = pack2(f0[0], f0[1]); ai[1] = pack2(f0[2], f0[3]);
      ai[2] = pack2(f1[0], f1[1]); ai[3] = pack2(f1[2], f1[3]);
      a[kc] = __builtin_bit_cast(s8v, ai);
    }
#pragma unroll
    for (int nf = 0; nf < 6; ++nf) {
      const int col = cg * 96 + nf * 16 + n;
      const s8v b0 = *(const s8v*)&Ws[bw][col][(((0 + quad) - col) & 7) * 8];
      const s8v b1 = *(const s8v*)&Ws[bw][col][(((4 + quad) - col) & 7) * 8];
      acc[nf] = __builtin_amdgcn_mfma_f32_16x16x32_bf16(a[0], b0, acc[nf], 0, 0, 0);
      acc[nf] = __builtin_amdgcn_mfma_f32_16x16x32_bf16(a[1], b1, acc[nf], 0, 0, 0);
    }
  };

  // prologue: W0 first, then X0..X2 (FIFO: waiting for X0 keeps X1,X2 in flight)
  dmaW(0, 0); dmaX(0, 0); dmaX(1, 1); dmaX(2, 2);
  wait_barrier<4>();

  for (int t = 0; t < 16; ++t) {
    if (t <= 14) dmaW(t + 1, (t + 1) & 1);   // W first (older in FIFO than this iter's X)
    if (t <= 12) dmaX(t + 3, (t + 3) & 3);
    compute(t & 1, t & 3);
    if (t <= 12)      wait_barrier<2>();     // keep X(t+3) flying; X(t+1),W(t+1) landed
    else if (t <= 14) wait_barrier<0>();     // tail
  }

  // epilogue: C row = quad*4+i, col = n (+16*nf)
#pragma unroll
  for (int nf = 0; nf < 6; ++nf) {
    const int gc = cg * 96 + nf * 16;
    const int p = gc >> 6;
    const int rcol = (gc & 63) + n;
#pragma unroll
    for (int i = 0; i < 4; ++i) {
      const int R = r0 + mg * 16 + quad * 4 + i;
      const float av = acc[nf][i];
      if (p == 0)      qo[(size_t)R * HD + rcol] = f2bf(av);
      else if (p == 1) ko[(size_t)R * HD + rcol] = f2bf(av);
      else {
        // V transposed [b][d][t'] + key-order swizzle so attn PV B-frags are single 16B loads
        const int t2 = R & (TS - 1), b = t2 & 31;
        const int pos = (t2 & ~31) | (((b >> 2) & 3) << 3) | (((b >> 4) & 1) << 2) | (b & 3);
        vo[(size_t)(R >> 11) * HD * TS + (size_t)rcol * TS + pos] = (_Float16)av;
      }
    }
  }
}

// ---- kernel 2: attention. grid 256 x 512 thr (8 waves). 64 q/block.
// Waves = 2 q-groups (32 q each) x 4 key-quarters (512 keys = 8 chunks of 64).
// K AND V staged in LDS, 2-buf each: 128 KB, 1 block/CU, 8 waves.
// SINGLE barrier per iteration: prefetch for chunk t+1 is issued at the TOP of iter t
// (the previous iter's wait_barrier lgkmcnt(0) already retired all reads of the target
// buffer -> no WAR hazard), then one vmcnt(0)+barrier at the END. The prefetch has the
// whole compute body (~1300 cyc) to cover ~250 cyc L2-resident latency, so the drain is
// nearly free. 14 -> 8 block-wide syncs vs R2, and no mid-iteration serialization.
// S^T = K Q^T -> exp2 in-reg -> f16 PV; l via P*ones. 4-way combine in LDS overlay.
__global__ __launch_bounds__(512) void attn_kernel(
    const short* __restrict__ q, const short* __restrict__ k,
    const _Float16* __restrict__ vT, float* __restrict__ out)
{
  __shared__ __align__(16) char smem[131072];  // K[4][2][64][64]s (64KB) | V[4][2][64][64]h (64KB)
  const int tid = threadIdx.x;
  const int wv = tid >> 6, lane = tid & 63, n = lane & 15, quad = lane >> 4;
  const int kq = wv & 3, qg = wv >> 2;         // key-quarter, q-group
  const int batch = blockIdx.x & 7;            // XCD swizzle: batch K/V pinned per XCD L2
  const int qgb = blockIdx.x >> 3;
  const int m0 = batch * TS + qgb * 64;
  const short*    kb = k  + (size_t)batch * TS * HD;
  const _Float16* vb = vT + (size_t)batch * HD * TS;
  const int drow = lane >> 3, dslot = lane & 7;
  const f4 fz = {0.f, 0.f, 0.f, 0.f};

  auto kbuf = [&](int buf) { return (short*)   (smem +         (kq * 2 + buf) * 8192); };
  auto vbuf = [&](int buf) { return (_Float16*)(smem + 65536 + (kq * 2 + buf) * 8192); };

  // stage one 64-key K+V chunk for this quarter; 2 waves (qg 0/1) split rows 4 ways each
  auto dmaKV = [&](int tt, int buf) {
    const int c = kq * 8 + tt;
#pragma unroll
    for (int u = 0; u < 4; ++u) {
      const int K0 = (qg * 4 + u) * 8;
      const int key = K0 + drow;
      const int gs = (dslot + key) & 7;
      gl2lds(&kb[(size_t)(c * 64 + key) * HD + gs * 8], kbuf(buf) + K0 * 64);
    }
#pragma unroll
    for (int u = 0; u < 4; ++u) {
      const int D0 = (qg * 4 + u) * 8;
      const int d = D0 + drow;
      const int gs = (dslot + d) & 7;
      gl2lds(&vb[(size_t)d * TS + c * 64 + gs * 8], vbuf(buf) + D0 * 64);
    }
  };

  s8v qf[2][2];
#pragma unroll
  for (int qh = 0; qh < 2; ++qh)
#pragma unroll
    for (int kc = 0; kc < 2; ++kc)
      qf[qh][kc] = *(const s8v*)&q[(size_t)(m0 + qg * 32 + qh * 16 + n) * HD + kc * 32 + quad * 8];

  f4 o[2][4] = {{fz, fz, fz, fz}, {fz, fz, fz, fz}};
  f4 lD[2] = {fz, fz};
  h8 ones;
#pragma unroll
  for (int j = 0; j < 8; ++j) ones[j] = (_Float16)1.0f;

  dmaKV(0, 0); dmaKV(1, 1);   // 8 ops each
  wait_barrier<8>();          // chunk 0 landed; chunk 1's 8 ops in flight

  for (int t = 0; t < 8; ++t) {
    const int buf = t & 1;

    // prefetch chunk t+1 into the buffer consumed at t-1 (WAR-safe: prior barrier's
    // lgkmcnt(0) retired all its readers). t=0's chunk 1 came from the prologue.
    if (t >= 1 && t <= 6) dmaKV(t + 1, (t + 1) & 1);

    const short*    ks = kbuf(buf);
    const _Float16* vs = vbuf(buf);

    // QK^T: per key-fragment, feed both q-groups immediately (short kf live range)
    f4 st[2][4];
#pragma unroll
    for (int f = 0; f < 4; ++f) {
      const int key = f * 16 + n;
      const s8v k0 = *(const s8v*)&ks[key * 64 + (((0 + quad) - key) & 7) * 8];
      const s8v k1 = *(const s8v*)&ks[key * 64 + (((4 + quad) - key) & 7) * 8];
#pragma unroll
      for (int qh = 0; qh < 2; ++qh) {
        st[qh][f] = __builtin_amdgcn_mfma_f32_16x16x32_bf16(k0, qf[qh][0], fz, 0, 0, 0);
        st[qh][f] = __builtin_amdgcn_mfma_f32_16x16x32_bf16(k1, qf[qh][1], st[qh][f], 0, 0, 0);
      }
    }

    h8 pa[2][2];
#pragma unroll
    for (int qh = 0; qh < 2; ++qh)
#pragma unroll
      for (int pr = 0; pr < 2; ++pr)
#pragma unroll
        for (int hf = 0; hf < 2; ++hf)
#pragma unroll
          for (int i = 0; i < 4; ++i)
            pa[qh][pr][hf * 4 + i] = (_Float16)__builtin_amdgcn_exp2f(st[qh][pr * 2 + hf][i]);

#pragma unroll
    for (int pr = 0; pr < 2; ++pr) {
#pragma unroll
      for (int qh = 0; qh < 2; ++qh)
        lD[qh] = __builtin_amdgcn_mfma_f32_16x16x32_f16(pa[qh][pr], ones, lD[qh], 0, 0, 0);
#pragma unroll
      for (int g = 0; g < 4; ++g) {
        const int d = g * 16 + n;
        const h8 vf = *(const h8*)&vs[d * 64 + (((pr * 4 + quad) - d) & 7) * 8];
#pragma unroll
        for (int qh = 0; qh < 2; ++qh)
          o[qh][g] = __builtin_amdgcn_mfma_f32_16x16x32_f16(pa[qh][pr], vf, o[qh][g], 0, 0, 0);
      }
    }

    // single sync point per iteration: chunk t+1 fully landed (it had the whole
    // compute body of cover); nothing else outstanding -> vmcnt(0) is cheap here.
    if (t <= 6) wait_barrier<0>();
  }

  __syncthreads();   // all waves done with K/V LDS before overlay

  float* o_c = (float*)smem;              // [4 kq][64 q][68]  (68 pad: 2-way banks, 16B-aligned)
  float* l_c = (float*)(smem + 69632);    // [4 kq][64 q]
  if (n == 0)
#pragma unroll
    for (int qh = 0; qh < 2; ++qh)
#pragma unroll
      for (int i = 0; i < 4; ++i)
        l_c[kq * 64 + qg * 32 + qh * 16 + quad * 4 + i] = lD[qh][i];
#pragma unroll
  for (int qh = 0; qh < 2; ++qh)
#pragma unroll
    for (int g = 0; g < 4; ++g)
#pragma unroll
      for (int i = 0; i < 4; ++i)
        o_c[kq * 4352 + (qg * 32 + qh * 16 + quad * 4 + i) * 68 + g * 16 + n] = o[qh][g][i];
  __syncthreads();

  // combine quarters: 1024 output-groups (64 q x 16 d4), 512 thr x 2 reps
#pragma unroll
  for (int rep = 0; rep < 2; ++rep) {
    const int idx = tid + rep * 512;
    const int qr = idx >> 4, d4 = (idx & 15) * 4;
    float L = 0.f;
    f4 r = fz;
#pragma unroll
    for (int c2 = 0; c2 < 4; ++c2) {
      L += l_c[c2 * 64 + qr];
      r += *(const f4*)&o_c[c2 * 4352 + qr * 68 + d4];
    }
    const float inv = 1.0f / L;
    r[0] *= inv; r[1] *= inv; r[2] *= inv; r[3] *= inv;
    *(f4*)&out[(size_t)(m0 + qr) * HD + d4] = r;
  }
}

extern "C" void kernel_launch(void* const* d_in, const int* in_sizes, int n_in,
                              void* d_out, int out_size, void* d_ws, size_t ws_size,
                              hipStream_t stream) {
  const float* x  = (const float*)d_in[0];
  const float* Wk = (const float*)d_in[1];
  const float* Wq = (const float*)d_in[2];
  const float* Wv = (const float*)d_in[3];
  float* out = (float*)d_out;

  short* qb = (short*)d_ws;                           // [MTOT][64] bf16 (pre-scaled)
  short* kb = qb + (size_t)MTOT * HD;                 // [MTOT][64] bf16
  _Float16* vb = (_Float16*)(kb + (size_t)MTOT * HD); // [NB][64][TS] f16, key-swizzled
  short* wb = (short*)(vb + (size_t)NB * HD * TS);    // [192][1024] bf16 weights

  wconv_kernel<<<192, 256, 0, stream>>>(Wk, Wq, Wv, wb);
  proj_kernel<<<MTOT / 32, 256, 0, stream>>>(x, wb, qb, kb, vb);
  attn_kernel<<<MTOT / 64, 512, 0, stream>>>(qb, kb, vb, out);
}